// Round 1
// baseline (323.854 us; speedup 1.0000x reference)
//
#include <hip/hip_runtime.h>

// Problem constants (from reference)
#define BATCH 32
#define NB    64
#define CH    8
#define CORE  32
#define RES   64
#define POS   16                          // (RES-CORE)/2
#define DIM   (CORE*CORE*CORE*CH)         // 262144
#define OUT_PER_B (CH*RES*RES*RES)        // 2097152

#define CORE_BLOCKS (DIM/256)                       // 1024
#define ZERO_BLOCKS ((BATCH*OUT_PER_B/4)/256)       // 65536

// Kernel A: s_t[k*32 + b] = z[b*NB + k] * L[k]   (transposed so b is contiguous
// -> main kernel's uniform loads merge into s_load_dwordx4/x8)
__global__ void prep_s_kernel(const float* __restrict__ z,
                              const float* __restrict__ L,
                              float* __restrict__ st) {
    int t = threadIdx.x;  // 256 threads
#pragma unroll
    for (int r = 0; r < 8; ++r) {
        int idx = r * 256 + t;     // 0..2047, idx = k*32 + b
        int k = idx >> 5;
        int b = idx & 31;
        st[idx] = z[b * NB + k] * L[k];
    }
}

// Fused kernel:
//  blocks [0, CORE_BLOCKS): compute core GEMM, write into placed positions
//  blocks [CORE_BLOCKS, CORE_BLOCKS+ZERO_BLOCKS): write float4 zeros to periphery
__global__ __launch_bounds__(256) void core_part_kernel(
        const float* __restrict__ U,
        const float* __restrict__ mu,
        const float* __restrict__ st,
        float* __restrict__ out) {
    int bid = blockIdx.x;
    if (bid < CORE_BLOCKS) {
        // ---- core GEMM: out[b, place(d)] = sum_k st[k][b] * U[k][d] + mu[d]
        const int d = bid * 256 + threadIdx.x;   // 0..DIM-1
        float acc[BATCH];
#pragma unroll
        for (int b = 0; b < BATCH; ++b) acc[b] = 0.0f;

#pragma unroll 8
        for (int k = 0; k < NB; ++k) {
            const float u = U[(size_t)k * DIM + d];      // coalesced across lanes
            const float* sk = st + k * BATCH;            // wave-uniform -> s_load
#pragma unroll
            for (int b = 0; b < BATCH; ++b) {
                acc[b] += sk[b] * u;                     // v_fmac_f32 (sgpr, vgpr)
            }
        }

        const float m = mu[d];
        // d -> (c, i, j, kk) in 8x32x32x32
        const int c  = d >> 15;
        const int i  = (d >> 10) & 31;
        const int j  = (d >> 5) & 31;
        const int kk = d & 31;
        const size_t o = (size_t)c * (RES * RES * RES)
                       + (size_t)(i + POS) * (RES * RES)
                       + (size_t)(j + POS) * RES
                       + (size_t)(kk + POS);
#pragma unroll
        for (int b = 0; b < BATCH; ++b) {
            out[(size_t)b * OUT_PER_B + o] = acc[b] + m;
        }
    } else {
        // ---- periphery zeroing, one float4 per thread over the whole output;
        // skip groups fully inside the core (partition is exact: core k-range
        // [16,48) == float4 groups [4,12)).
        const size_t gid4 = (size_t)(bid - CORE_BLOCKS) * 256 + threadIdx.x;
        const int rem = (int)(gid4 & 65535);   // within one (b,c) 64^3/4 chunk
        const int i = rem >> 10;
        const int j = (rem >> 4) & 63;
        const int g = rem & 15;
        const bool in_core = (i >= POS) & (i < POS + CORE) &
                             (j >= POS) & (j < POS + CORE) &
                             (g >= 4) & (g < 12);
        if (!in_core) {
            float4* o4 = (float4*)out;
            o4[gid4] = make_float4(0.f, 0.f, 0.f, 0.f);
        }
    }
}

extern "C" void kernel_launch(void* const* d_in, const int* in_sizes, int n_in,
                              void* d_out, int out_size, void* d_ws, size_t ws_size,
                              hipStream_t stream) {
    const float* z  = (const float*)d_in[0];   // (32, 64)
    const float* U  = (const float*)d_in[1];   // (64, 262144)
    const float* L  = (const float*)d_in[2];   // (64,)
    const float* mu = (const float*)d_in[3];   // (262144,)
    float* out = (float*)d_out;                // (32, 8, 64, 64, 64)
    float* st  = (float*)d_ws;                 // 2048 floats scratch

    prep_s_kernel<<<1, 256, 0, stream>>>(z, L, st);
    core_part_kernel<<<CORE_BLOCKS + ZERO_BLOCKS, 256, 0, stream>>>(U, mu, st, out);
}

// Round 2
// 322.819 us; speedup vs baseline: 1.0032x; 1.0032x over previous
//
#include <hip/hip_runtime.h>

// Problem constants (from reference)
#define BATCH 32
#define NB    64
#define CH    8
#define CORE  32
#define RES   64
#define POS   16                          // (RES-CORE)/2
#define DIM   (CORE*CORE*CORE*CH)         // 262144
#define OUT_PER_B (CH*RES*RES*RES)        // 2097152

#define DPT   2                                       // d's per core thread
#define CORE_BLOCKS (DIM/(256*DPT))                   // 512
#define ZERO_BLOCKS ((BATCH*OUT_PER_B/4)/256)         // 65536

// Fused kernel:
//  blocks [0, CORE_BLOCKS): compute core GEMM (st staged in LDS), write placed
//  blocks [CORE_BLOCKS, ...): write float4 zeros to periphery (exact partition)
__global__ __launch_bounds__(256) void core_part_kernel(
        const float* __restrict__ U,
        const float* __restrict__ mu,
        const float* __restrict__ z,
        const float* __restrict__ L,
        float* __restrict__ out) {
    const int bid = blockIdx.x;
    if (bid < CORE_BLOCKS) {
        // ---- stage st[k*32+b] = z[b,k]*L[k] into LDS (8 KB)
        __shared__ float st[NB * BATCH];
        const int tid = threadIdx.x;
#pragma unroll
        for (int r = 0; r < 8; ++r) {
            const int idx = r * 256 + tid;   // idx = k*32 + b
            const int k = idx >> 5;
            const int b = idx & 31;
            st[idx] = z[b * NB + k] * L[k];
        }
        __syncthreads();

        // ---- core GEMM: out[b, place(d)] = sum_k st[k][b] * U[k][d] + mu[d]
        const int d0 = (bid * 256 + tid) * DPT;   // two consecutive d's
        float acc0[BATCH], acc1[BATCH];
#pragma unroll
        for (int b = 0; b < BATCH; ++b) { acc0[b] = 0.f; acc1[b] = 0.f; }

#pragma unroll 2
        for (int k = 0; k < NB; ++k) {
            const float2 u = *(const float2*)&U[(size_t)k * DIM + d0]; // coalesced
#pragma unroll
            for (int q = 0; q < 8; ++q) {
                // wave-uniform LDS address -> broadcast, conflict-free
                const float4 s = *(const float4*)&st[k * BATCH + q * 4];
                acc0[q*4+0] += s.x * u.x;  acc1[q*4+0] += s.x * u.y;
                acc0[q*4+1] += s.y * u.x;  acc1[q*4+1] += s.y * u.y;
                acc0[q*4+2] += s.z * u.x;  acc1[q*4+2] += s.z * u.y;
                acc0[q*4+3] += s.w * u.x;  acc1[q*4+3] += s.w * u.y;
            }
        }

        const float2 m = *(const float2*)&mu[d0];
        // d0 -> (c, i, j, kk) in 8x32x32x32 ; d0 even so d0,d0+1 share a row
        const int c  = d0 >> 15;
        const int i  = (d0 >> 10) & 31;
        const int j  = (d0 >> 5) & 31;
        const int kk = d0 & 31;
        const size_t o = (size_t)c * (RES * RES * RES)
                       + (size_t)(i + POS) * (RES * RES)
                       + (size_t)(j + POS) * RES
                       + (size_t)(kk + POS);
#pragma unroll
        for (int b = 0; b < BATCH; ++b) {
            float2 v = make_float2(acc0[b] + m.x, acc1[b] + m.y);
            *(float2*)&out[(size_t)b * OUT_PER_B + o] = v;   // 8B-aligned
        }
    } else {
        // ---- periphery zeroing, one float4 per thread; skip groups fully
        // inside the core (exact partition: kk in [16,48) == groups [4,12)).
        const size_t gid4 = (size_t)(bid - CORE_BLOCKS) * 256 + threadIdx.x;
        const int rem = (int)(gid4 & 65535);   // within one (b,c) 64^3/4 chunk
        const int i = rem >> 10;
        const int j = (rem >> 4) & 63;
        const int g = rem & 15;
        const bool in_core = (i >= POS) & (i < POS + CORE) &
                             (j >= POS) & (j < POS + CORE) &
                             (g >= 4) & (g < 12);
        if (!in_core) {
            float4* o4 = (float4*)out;
            o4[gid4] = make_float4(0.f, 0.f, 0.f, 0.f);
        }
    }
}

extern "C" void kernel_launch(void* const* d_in, const int* in_sizes, int n_in,
                              void* d_out, int out_size, void* d_ws, size_t ws_size,
                              hipStream_t stream) {
    const float* z  = (const float*)d_in[0];   // (32, 64)
    const float* U  = (const float*)d_in[1];   // (64, 262144)
    const float* L  = (const float*)d_in[2];   // (64,)
    const float* mu = (const float*)d_in[3];   // (262144,)
    float* out = (float*)d_out;                // (32, 8, 64, 64, 64)

    core_part_kernel<<<CORE_BLOCKS + ZERO_BLOCKS, 256, 0, stream>>>(U, mu, z, L, out);
}